// Round 5
// baseline (353.261 us; speedup 1.0000x reference)
//
#include <hip/hip_runtime.h>

// PureGCN forward. R5: SpMM reworked to 2 dst-rows/wave with 8B/lane gathers
// (2x memory-level parallelism, half the waves); residual stored bf16 in d_out
// scratch; k_scan folded into k_build; W bf16-convert folded into GEMM staging.

constexpr int N_NODES = 100000;
constexpr int N_EDGES = 1600000;
constexpr int HID     = 128;
constexpr int NBKT    = (N_NODES + 511) / 512;   // 196 buckets of 512 nodes
constexpr int BCAP    = 9216;                    // bucket capacity (mean 8192)
constexpr float LN_EPS = 1e-5f;

typedef __attribute__((ext_vector_type(8))) short short8;   // 8 bf16
typedef __attribute__((ext_vector_type(4))) float floatx4;  // MFMA acc

__device__ inline unsigned pack_bf16x2(float a, float b) {
    unsigned ua = __float_as_uint(a), ub = __float_as_uint(b);
    ua += 0x7fff + ((ua >> 16) & 1);          // RNE
    ub += 0x7fff + ((ub >> 16) & 1);
    return (ua >> 16) | (ub & 0xffff0000u);
}
__device__ inline float bflo(unsigned u) { return __uint_as_float(u << 16); }
__device__ inline float bfhi(unsigned u) { return __uint_as_float(u & 0xffff0000u); }

// ---------------- phase 1: bucket edges by dst>>9 (LDS multisplit) ----------------
__global__ __launch_bounds__(256) void k_bin(const int* __restrict__ ei,
                                             const float* __restrict__ ef,
                                             int* __restrict__ gcur,
                                             int* __restrict__ gbufDst,
                                             int2* __restrict__ gbufSW) {
    __shared__ int cnt[NBKT];
    __shared__ int incl[256];
    __shared__ int gbase[NBKT];
    __shared__ int sdst[2048];
    __shared__ int2 ssw[2048];
    const int t = threadIdx.x;

    for (int e0 = blockIdx.x * 2048; e0 < N_EDGES; e0 += gridDim.x * 2048) {
        for (int i = t; i < NBKT; i += 256) cnt[i] = 0;
        __syncthreads();

        const int nE = min(2048, N_EDGES - e0);
        int ed[8], es[8], ep[8]; float ew[8];
        const int base = e0 + t * 8;
        if (base + 8 <= N_EDGES) {
            int4 s0 = *(const int4*)&ei[base];
            int4 s1 = *(const int4*)&ei[base + 4];
            int4 d0 = *(const int4*)&ei[N_EDGES + base];
            int4 d1 = *(const int4*)&ei[N_EDGES + base + 4];
            float4 w0 = *(const float4*)&ef[base];
            float4 w1 = *(const float4*)&ef[base + 4];
            es[0]=s0.x; es[1]=s0.y; es[2]=s0.z; es[3]=s0.w;
            es[4]=s1.x; es[5]=s1.y; es[6]=s1.z; es[7]=s1.w;
            ed[0]=d0.x; ed[1]=d0.y; ed[2]=d0.z; ed[3]=d0.w;
            ed[4]=d1.x; ed[5]=d1.y; ed[6]=d1.z; ed[7]=d1.w;
            ew[0]=w0.x; ew[1]=w0.y; ew[2]=w0.z; ew[3]=w0.w;
            ew[4]=w1.x; ew[5]=w1.y; ew[6]=w1.z; ew[7]=w1.w;
#pragma unroll
            for (int k = 0; k < 8; ++k) ep[k] = atomicAdd(&cnt[ed[k] >> 9], 1);
        } else {
#pragma unroll
            for (int k = 0; k < 8; ++k) {
                int idx = base + k;
                if (idx < N_EDGES) {
                    es[k] = ei[idx]; ed[k] = ei[N_EDGES + idx]; ew[k] = ef[idx];
                    ep[k] = atomicAdd(&cnt[ed[k] >> 9], 1);
                } else ed[k] = -1;
            }
        }
        __syncthreads();

        int v = (t < NBKT) ? cnt[t] : 0;
        incl[t] = v;
        for (int o = 1; o < 256; o <<= 1) {
            __syncthreads();
            int u = (t >= o) ? incl[t - o] : 0;
            __syncthreads();
            incl[t] += u;
        }
        __syncthreads();
        if (t < NBKT) gbase[t] = atomicAdd(&gcur[t], v);
        __syncthreads();

#pragma unroll
        for (int k = 0; k < 8; ++k) {
            if (ed[k] < 0) continue;
            int b = ed[k] >> 9;
            int idx = incl[b] - cnt[b] + ep[k];
            sdst[idx] = ed[k];
            ssw[idx] = make_int2(es[k], __float_as_int(ew[k]));
        }
        __syncthreads();

        for (int j = t; j < nE; j += 256) {
            int d = sdst[j];
            int b = d >> 9;
            int pos = gbase[b] + (j - (incl[b] - cnt[b]));
            if (pos < BCAP) {
                gbufDst[(size_t)b * BCAP + pos] = d;
                gbufSW [(size_t)b * BCAP + pos] = ssw[j];
            }
        }
        __syncthreads();
    }
}

// ---------------- phase 2: per-bucket counting sort -> dense CSR ----------------
// (bucket-base prefix scan inlined; rp[N]=E written by last block)
__global__ __launch_bounds__(512) void k_build(const int* __restrict__ gcur,
                                               const int* __restrict__ gbufDst,
                                               const int2* __restrict__ gbufSW,
                                               int* __restrict__ rp,
                                               int2* __restrict__ csr) {
    __shared__ int cnt[512];
    __shared__ int cur[512];
    __shared__ int2 sorted[BCAP];
    const int t     = threadIdx.x;
    const int b     = blockIdx.x;
    const int nbase = b * 512;

    // inline bucket-base scan over min(gcur[*],BCAP)
    int v0 = (t < NBKT) ? min(gcur[t], BCAP) : 0;
    cnt[t] = v0;
    for (int o = 1; o < 512; o <<= 1) {
        __syncthreads();
        int u = (t >= o) ? cnt[t - o] : 0;
        __syncthreads();
        cnt[t] += u;
    }
    __syncthreads();
    const int nb = min(gcur[b], BCAP);
    const int cb = cnt[b] - nb;                   // exclusive prefix at b
    if (b == NBKT - 1 && t == 0) rp[N_NODES] = cnt[NBKT - 1];
    __syncthreads();

    const int*  bd = gbufDst + (size_t)b * BCAP;
    const int2* bs = gbufSW  + (size_t)b * BCAP;

    cnt[t] = 0;
    __syncthreads();
    for (int i = t; i < nb; i += 512) atomicAdd(&cnt[bd[i] - nbase], 1);
    __syncthreads();

    int v = cnt[t];
    for (int o = 1; o < 512; o <<= 1) {
        __syncthreads();
        int u = (t >= o) ? cnt[t - o] : 0;
        __syncthreads();
        cnt[t] += u;
    }
    __syncthreads();
    const int excl = cnt[t] - v;
    cur[t] = excl;
    if (nbase + t < N_NODES) rp[nbase + t] = cb + excl;
    __syncthreads();

    for (int i = t; i < nb; i += 512) {
        int d = bd[i];
        int pos = atomicAdd(&cur[d - nbase], 1);
        sorted[pos] = bs[i];
    }
    __syncthreads();
    for (int i = t; i < nb; i += 512) csr[(size_t)cb + i] = sorted[i];
}

// ---------------- MFMA GEMM + LN0 + ReLU ----------------
// writes orib (bf16 pre-LN, residual source) and hact (bf16 post-LN/ReLU)
__global__ __launch_bounds__(256) void k_gemm_mfma(const float* __restrict__ x,
                                                   const float* __restrict__ W,
                                                   const float* __restrict__ bias,
                                                   const float* __restrict__ lns,
                                                   const float* __restrict__ lnb,
                                                   unsigned* __restrict__ orib,
                                                   unsigned* __restrict__ hact) {
    __shared__ __align__(16) char smem[128 * 136 * 2 + 64 * 136 * 2];
    ushort (*Ws)[136] = (ushort(*)[136])smem;
    ushort (*Xs)[136] = (ushort(*)[136])(smem + 128 * 136 * 2);
    float  (*Hs)[132] = (float(*)[132])smem;

    const int t    = threadIdx.x;
    const int row0 = blockIdx.x * 64;

    {   // stage W fp32 -> bf16 (2048 chunks of 8 values)
        const float4* Wf = (const float4*)W;
#pragma unroll
        for (int i = 0; i < 8; ++i) {
            int g = t + 256 * i;
            float4 p = Wf[g * 2], q = Wf[g * 2 + 1];
            uint4 vv = make_uint4(pack_bf16x2(p.x, p.y), pack_bf16x2(p.z, p.w),
                                  pack_bf16x2(q.x, q.y), pack_bf16x2(q.z, q.w));
            int r = g >> 4;
            int c = (g & 15) * 8;
            *(uint4*)&Ws[r][c] = vv;
        }
    }
    {   // stage x tile -> bf16
        const float4* xg = (const float4*)x;
        const int base = blockIdx.x * 2048;
#pragma unroll
        for (int i = 0; i < 8; ++i) {
            int f = t + 256 * i;
            int g = base + f;
            float4 vv = make_float4(0.f, 0.f, 0.f, 0.f);
            if (g < N_NODES * 32) vv = xg[g];
            int r = f >> 5;
            int c = (f & 31) * 4;
            uint2 p = make_uint2(pack_bf16x2(vv.x, vv.y), pack_bf16x2(vv.z, vv.w));
            *(uint2*)&Xs[r][c] = p;
        }
    }
    __syncthreads();

    const int wv   = t >> 6;
    const int l    = t & 63;
    const int mrow = l & 15;
    const int kq   = l >> 4;

    floatx4 acc[8];
#pragma unroll
    for (int i = 0; i < 8; ++i) acc[i] = (floatx4){0.f, 0.f, 0.f, 0.f};

#pragma unroll
    for (int ks = 0; ks < 4; ++ks) {
        short8 a = *(const short8*)&Xs[wv * 16 + mrow][ks * 32 + kq * 8];
#pragma unroll
        for (int tc = 0; tc < 8; ++tc) {
            short8 bb = *(const short8*)&Ws[tc * 16 + mrow][ks * 32 + kq * 8];
            acc[tc] = __builtin_amdgcn_mfma_f32_16x16x32_bf16(a, bb, acc[tc], 0, 0, 0);
        }
    }
    __syncthreads();

#pragma unroll
    for (int tc = 0; tc < 8; ++tc)
#pragma unroll
        for (int r = 0; r < 4; ++r)
            Hs[wv * 16 + kq * 4 + r][tc * 16 + mrow] = acc[tc][r];
    __syncthreads();

    const float2 b2  = ((const float2*)bias)[l];
    const float2 sc2 = ((const float2*)lns)[l];
    const float2 bb2 = ((const float2*)lnb)[l];
    for (int rr = 0; rr < 16; ++rr) {
        const int lrow = wv * 16 + rr;
        const int grow = row0 + lrow;
        if (grow >= N_NODES) break;
        float2 vv = *(const float2*)&Hs[lrow][l * 2];
        vv.x += b2.x; vv.y += b2.y;
        orib[(size_t)grow * 64 + l] = pack_bf16x2(vv.x, vv.y);
        float s  = vv.x + vv.y;
        float s2 = vv.x * vv.x + vv.y * vv.y;
#pragma unroll
        for (int m = 1; m < 64; m <<= 1) {
            s  += __shfl_xor(s, m);
            s2 += __shfl_xor(s2, m);
        }
        const float mu   = s * (1.0f / 128.0f);
        const float var  = s2 * (1.0f / 128.0f) - mu * mu;
        const float rstd = rsqrtf(var + LN_EPS);
        float y0 = fmaxf((vv.x - mu) * rstd * sc2.x + bb2.x, 0.0f);
        float y1 = fmaxf((vv.y - mu) * rstd * sc2.y + bb2.y, 0.0f);
        hact[(size_t)grow * 64 + l] = pack_bf16x2(y0, y1);
    }
}

// ---------------- SpMM: 2 dst rows per wave, 8B/lane gathers ----------------
// lanes 0-31 -> node 2*wid, lanes 32-63 -> node 2*wid+1; lane covers 4 channels.
__device__ inline void spmm_body(const int* __restrict__ rp,
                                 const int2* __restrict__ csr,
                                 const uint2* __restrict__ H2,
                                 int n, int l32, int deg, int beg, int maxd,
                                 float& a0, float& a1, float& a2, float& a3) {
    for (int j = 0; j < maxd; j += 4) {
#pragma unroll
        for (int k = 0; k < 4; ++k) {
            const int jj = j + k;
            const bool valid = jj < deg;
            const int idx = valid ? beg + jj : 0;
            int2 c = csr[idx];
            float w = valid ? __int_as_float(c.y) : 0.0f;
            uint2 v = H2[(size_t)c.x * 32 + l32];
            a0 += w * bflo(v.x);
            a1 += w * bfhi(v.x);
            a2 += w * bflo(v.y);
            a3 += w * bfhi(v.y);
        }
    }
}

__global__ __launch_bounds__(256) void k_spmm_ln(const int* __restrict__ rp,
                                                 const int2* __restrict__ csr,
                                                 const unsigned* __restrict__ Hb,
                                                 const unsigned* __restrict__ orib,
                                                 const float* __restrict__ lns,
                                                 const float* __restrict__ lnb,
                                                 unsigned* __restrict__ hout) {
    const int wid  = (blockIdx.x * 256 + threadIdx.x) >> 6;
    const int lane = threadIdx.x & 63;
    const int half = lane >> 5;
    const int l32  = lane & 31;
    const int n    = wid * 2 + half;

    const int beg = rp[n];
    const int deg = rp[n + 1] - beg;
    int maxd = deg;
    maxd = max(maxd, __shfl_xor(maxd, 32));

    float a0 = 0.f, a1 = 0.f, a2 = 0.f, a3 = 0.f;
    spmm_body(rp, csr, (const uint2*)Hb, n, l32, deg, beg, maxd, a0, a1, a2, a3);

    // residual (bf16) + LN + ReLU -> bf16
    uint2 o = ((const uint2*)orib)[(size_t)n * 32 + l32];
    float v0 = a0 + bflo(o.x), v1 = a1 + bfhi(o.x);
    float v2 = a2 + bflo(o.y), v3 = a3 + bfhi(o.y);
    float s  = v0 + v1 + v2 + v3;
    float s2 = v0 * v0 + v1 * v1 + v2 * v2 + v3 * v3;
#pragma unroll
    for (int m = 1; m < 32; m <<= 1) {
        s  += __shfl_xor(s, m);
        s2 += __shfl_xor(s2, m);
    }
    const float mu   = s * (1.0f / 128.0f);
    const float var  = s2 * (1.0f / 128.0f) - mu * mu;
    const float rstd = rsqrtf(var + LN_EPS);
    const float4 sc = ((const float4*)lns)[l32];
    const float4 bb = ((const float4*)lnb)[l32];
    float y0 = fmaxf((v0 - mu) * rstd * sc.x + bb.x, 0.0f);
    float y1 = fmaxf((v1 - mu) * rstd * sc.y + bb.y, 0.0f);
    float y2 = fmaxf((v2 - mu) * rstd * sc.z + bb.z, 0.0f);
    float y3 = fmaxf((v3 - mu) * rstd * sc.w + bb.w, 0.0f);
    ((uint2*)hout)[(size_t)n * 32 + l32] =
        make_uint2(pack_bf16x2(y0, y1), pack_bf16x2(y2, y3));
}

__global__ __launch_bounds__(256) void k_spmm_out(const int* __restrict__ rp,
                                                  const int2* __restrict__ csr,
                                                  const unsigned* __restrict__ Hb,
                                                  float* __restrict__ out) {
    const int wid  = (blockIdx.x * 256 + threadIdx.x) >> 6;
    const int lane = threadIdx.x & 63;
    const int half = lane >> 5;
    const int l32  = lane & 31;
    const int n    = wid * 2 + half;

    const int beg = rp[n];
    const int deg = rp[n + 1] - beg;
    int maxd = deg;
    maxd = max(maxd, __shfl_xor(maxd, 32));

    float a0 = 0.f, a1 = 0.f, a2 = 0.f, a3 = 0.f;
    spmm_body(rp, csr, (const uint2*)Hb, n, l32, deg, beg, maxd, a0, a1, a2, a3);

    ((float4*)out)[(size_t)n * 32 + l32] = make_float4(a0, a1, a2, a3);
}

extern "C" void kernel_launch(void* const* d_in, const int* in_sizes, int n_in,
                              void* d_out, int out_size, void* d_ws, size_t ws_size,
                              hipStream_t stream) {
    const float* x   = (const float*)d_in[0];
    const int*   ei  = (const int*)d_in[1];
    const float* ef  = (const float*)d_in[2];
    const float* W   = (const float*)d_in[3];
    const float* b   = (const float*)d_in[4];
    const float* lns = (const float*)d_in[5];
    const float* lnb = (const float*)d_in[6];
    float* out = (float*)d_out;

    // bf16 residual parked in d_out's first 25.6MB (read by spmm_ln, then d_out
    // fully overwritten by spmm_out)
    unsigned* orib = (unsigned*)d_out;

    unsigned* hact  = (unsigned*)d_ws;                          // N*64 u32
    unsigned* hact2 = hact + (size_t)N_NODES * 64;              // N*64 u32
    int2* csr    = (int2*)(hact2 + (size_t)N_NODES * 64);       // E
    int2* gbufSW = csr + N_EDGES;                               // NBKT*BCAP
    int* gcur    = (int*)(gbufSW + (size_t)NBKT * BCAP);        // NBKT
    int* rp      = gcur + NBKT;                                 // N+1
    int* gbufDst = rp + (N_NODES + 1);                          // NBKT*BCAP

    const int sb = N_NODES / 2 * 64 / 256;                      // 12500 blocks

    hipMemsetAsync(gcur, 0, NBKT * sizeof(int), stream);
    k_bin<<<256, 256, 0, stream>>>(ei, ef, gcur, gbufDst, gbufSW);
    k_build<<<NBKT, 512, 0, stream>>>(gcur, gbufDst, gbufSW, rp, csr);

    k_gemm_mfma<<<(N_NODES + 63) / 64, 256, 0, stream>>>(x, W, b, lns, lnb, orib, hact);

    k_spmm_ln<<<sb, 256, 0, stream>>>(rp, csr, hact, orib, lns + HID, lnb + HID, hact2);
    k_spmm_out<<<sb, 256, 0, stream>>>(rp, csr, hact2, out);
}

// Round 6
// 311.320 us; speedup vs baseline: 1.1347x; 1.1347x over previous
//
#include <hip/hip_runtime.h>

// PureGCN forward. R6: SpMM reverted to R4-proven shape (1 node/wave, scalar
// row bounds via readfirstlane, 4B/lane row gathers) after R5's 2-row/wave
// variant regressed (vector csr loads + maxd predication waste). Kept from R5:
// bf16 residual in d_out scratch, folded scan, folded W conversion. New: 8-wide
// edge unroll for 2x outstanding gathers per wave.

constexpr int N_NODES = 100000;
constexpr int N_EDGES = 1600000;
constexpr int HID     = 128;
constexpr int NBKT    = (N_NODES + 511) / 512;   // 196 buckets of 512 nodes
constexpr int BCAP    = 9216;                    // bucket capacity (mean 8192)
constexpr float LN_EPS = 1e-5f;

typedef __attribute__((ext_vector_type(8))) short short8;   // 8 bf16
typedef __attribute__((ext_vector_type(4))) float floatx4;  // MFMA acc

__device__ inline unsigned pack_bf16x2(float a, float b) {
    unsigned ua = __float_as_uint(a), ub = __float_as_uint(b);
    ua += 0x7fff + ((ua >> 16) & 1);          // RNE
    ub += 0x7fff + ((ub >> 16) & 1);
    return (ua >> 16) | (ub & 0xffff0000u);
}
__device__ inline float bflo(unsigned u) { return __uint_as_float(u << 16); }
__device__ inline float bfhi(unsigned u) { return __uint_as_float(u & 0xffff0000u); }

// ---------------- phase 1: bucket edges by dst>>9 (LDS multisplit) ----------------
__global__ __launch_bounds__(256) void k_bin(const int* __restrict__ ei,
                                             const float* __restrict__ ef,
                                             int* __restrict__ gcur,
                                             int* __restrict__ gbufDst,
                                             int2* __restrict__ gbufSW) {
    __shared__ int cnt[NBKT];
    __shared__ int incl[256];
    __shared__ int gbase[NBKT];
    __shared__ int sdst[2048];
    __shared__ int2 ssw[2048];
    const int t = threadIdx.x;

    for (int e0 = blockIdx.x * 2048; e0 < N_EDGES; e0 += gridDim.x * 2048) {
        for (int i = t; i < NBKT; i += 256) cnt[i] = 0;
        __syncthreads();

        const int nE = min(2048, N_EDGES - e0);
        int ed[8], es[8], ep[8]; float ew[8];
        const int base = e0 + t * 8;
        if (base + 8 <= N_EDGES) {
            int4 s0 = *(const int4*)&ei[base];
            int4 s1 = *(const int4*)&ei[base + 4];
            int4 d0 = *(const int4*)&ei[N_EDGES + base];
            int4 d1 = *(const int4*)&ei[N_EDGES + base + 4];
            float4 w0 = *(const float4*)&ef[base];
            float4 w1 = *(const float4*)&ef[base + 4];
            es[0]=s0.x; es[1]=s0.y; es[2]=s0.z; es[3]=s0.w;
            es[4]=s1.x; es[5]=s1.y; es[6]=s1.z; es[7]=s1.w;
            ed[0]=d0.x; ed[1]=d0.y; ed[2]=d0.z; ed[3]=d0.w;
            ed[4]=d1.x; ed[5]=d1.y; ed[6]=d1.z; ed[7]=d1.w;
            ew[0]=w0.x; ew[1]=w0.y; ew[2]=w0.z; ew[3]=w0.w;
            ew[4]=w1.x; ew[5]=w1.y; ew[6]=w1.z; ew[7]=w1.w;
#pragma unroll
            for (int k = 0; k < 8; ++k) ep[k] = atomicAdd(&cnt[ed[k] >> 9], 1);
        } else {
#pragma unroll
            for (int k = 0; k < 8; ++k) {
                int idx = base + k;
                if (idx < N_EDGES) {
                    es[k] = ei[idx]; ed[k] = ei[N_EDGES + idx]; ew[k] = ef[idx];
                    ep[k] = atomicAdd(&cnt[ed[k] >> 9], 1);
                } else ed[k] = -1;
            }
        }
        __syncthreads();

        int v = (t < NBKT) ? cnt[t] : 0;
        incl[t] = v;
        for (int o = 1; o < 256; o <<= 1) {
            __syncthreads();
            int u = (t >= o) ? incl[t - o] : 0;
            __syncthreads();
            incl[t] += u;
        }
        __syncthreads();
        if (t < NBKT) gbase[t] = atomicAdd(&gcur[t], v);
        __syncthreads();

#pragma unroll
        for (int k = 0; k < 8; ++k) {
            if (ed[k] < 0) continue;
            int b = ed[k] >> 9;
            int idx = incl[b] - cnt[b] + ep[k];
            sdst[idx] = ed[k];
            ssw[idx] = make_int2(es[k], __float_as_int(ew[k]));
        }
        __syncthreads();

        for (int j = t; j < nE; j += 256) {
            int d = sdst[j];
            int b = d >> 9;
            int pos = gbase[b] + (j - (incl[b] - cnt[b]));
            if (pos < BCAP) {
                gbufDst[(size_t)b * BCAP + pos] = d;
                gbufSW [(size_t)b * BCAP + pos] = ssw[j];
            }
        }
        __syncthreads();
    }
}

// ---------------- phase 2: per-bucket counting sort -> dense CSR ----------------
__global__ __launch_bounds__(512) void k_build(const int* __restrict__ gcur,
                                               const int* __restrict__ gbufDst,
                                               const int2* __restrict__ gbufSW,
                                               int* __restrict__ rp,
                                               int2* __restrict__ csr) {
    __shared__ int cnt[512];
    __shared__ int cur[512];
    __shared__ int2 sorted[BCAP];
    const int t     = threadIdx.x;
    const int b     = blockIdx.x;
    const int nbase = b * 512;

    // inline bucket-base scan over min(gcur[*],BCAP)
    int v0 = (t < NBKT) ? min(gcur[t], BCAP) : 0;
    cnt[t] = v0;
    for (int o = 1; o < 512; o <<= 1) {
        __syncthreads();
        int u = (t >= o) ? cnt[t - o] : 0;
        __syncthreads();
        cnt[t] += u;
    }
    __syncthreads();
    const int nb = min(gcur[b], BCAP);
    const int cb = cnt[b] - nb;
    if (b == NBKT - 1 && t == 0) rp[N_NODES] = cnt[NBKT - 1];
    __syncthreads();

    const int*  bd = gbufDst + (size_t)b * BCAP;
    const int2* bs = gbufSW  + (size_t)b * BCAP;

    cnt[t] = 0;
    __syncthreads();
    for (int i = t; i < nb; i += 512) atomicAdd(&cnt[bd[i] - nbase], 1);
    __syncthreads();

    int v = cnt[t];
    for (int o = 1; o < 512; o <<= 1) {
        __syncthreads();
        int u = (t >= o) ? cnt[t - o] : 0;
        __syncthreads();
        cnt[t] += u;
    }
    __syncthreads();
    const int excl = cnt[t] - v;
    cur[t] = excl;
    if (nbase + t < N_NODES) rp[nbase + t] = cb + excl;
    __syncthreads();

    for (int i = t; i < nb; i += 512) {
        int d = bd[i];
        int pos = atomicAdd(&cur[d - nbase], 1);
        sorted[pos] = bs[i];
    }
    __syncthreads();
    for (int i = t; i < nb; i += 512) csr[(size_t)cb + i] = sorted[i];
}

// ---------------- MFMA GEMM + LN0 + ReLU ----------------
// writes orib (bf16 pre-LN, residual source) and hact (bf16 post-LN/ReLU)
__global__ __launch_bounds__(256) void k_gemm_mfma(const float* __restrict__ x,
                                                   const float* __restrict__ W,
                                                   const float* __restrict__ bias,
                                                   const float* __restrict__ lns,
                                                   const float* __restrict__ lnb,
                                                   unsigned* __restrict__ orib,
                                                   unsigned* __restrict__ hact) {
    __shared__ __align__(16) char smem[128 * 136 * 2 + 64 * 136 * 2];
    ushort (*Ws)[136] = (ushort(*)[136])smem;
    ushort (*Xs)[136] = (ushort(*)[136])(smem + 128 * 136 * 2);
    float  (*Hs)[132] = (float(*)[132])smem;

    const int t    = threadIdx.x;
    const int row0 = blockIdx.x * 64;

    {   // stage W fp32 -> bf16
        const float4* Wf = (const float4*)W;
#pragma unroll
        for (int i = 0; i < 8; ++i) {
            int g = t + 256 * i;
            float4 p = Wf[g * 2], q = Wf[g * 2 + 1];
            uint4 vv = make_uint4(pack_bf16x2(p.x, p.y), pack_bf16x2(p.z, p.w),
                                  pack_bf16x2(q.x, q.y), pack_bf16x2(q.z, q.w));
            int r = g >> 4;
            int c = (g & 15) * 8;
            *(uint4*)&Ws[r][c] = vv;
        }
    }
    {   // stage x tile -> bf16
        const float4* xg = (const float4*)x;
        const int base = blockIdx.x * 2048;
#pragma unroll
        for (int i = 0; i < 8; ++i) {
            int f = t + 256 * i;
            int g = base + f;
            float4 vv = make_float4(0.f, 0.f, 0.f, 0.f);
            if (g < N_NODES * 32) vv = xg[g];
            int r = f >> 5;
            int c = (f & 31) * 4;
            uint2 p = make_uint2(pack_bf16x2(vv.x, vv.y), pack_bf16x2(vv.z, vv.w));
            *(uint2*)&Xs[r][c] = p;
        }
    }
    __syncthreads();

    const int wv   = t >> 6;
    const int l    = t & 63;
    const int mrow = l & 15;
    const int kq   = l >> 4;

    floatx4 acc[8];
#pragma unroll
    for (int i = 0; i < 8; ++i) acc[i] = (floatx4){0.f, 0.f, 0.f, 0.f};

#pragma unroll
    for (int ks = 0; ks < 4; ++ks) {
        short8 a = *(const short8*)&Xs[wv * 16 + mrow][ks * 32 + kq * 8];
#pragma unroll
        for (int tc = 0; tc < 8; ++tc) {
            short8 bb = *(const short8*)&Ws[tc * 16 + mrow][ks * 32 + kq * 8];
            acc[tc] = __builtin_amdgcn_mfma_f32_16x16x32_bf16(a, bb, acc[tc], 0, 0, 0);
        }
    }
    __syncthreads();

#pragma unroll
    for (int tc = 0; tc < 8; ++tc)
#pragma unroll
        for (int r = 0; r < 4; ++r)
            Hs[wv * 16 + kq * 4 + r][tc * 16 + mrow] = acc[tc][r];
    __syncthreads();

    const float2 b2  = ((const float2*)bias)[l];
    const float2 sc2 = ((const float2*)lns)[l];
    const float2 bb2 = ((const float2*)lnb)[l];
    for (int rr = 0; rr < 16; ++rr) {
        const int lrow = wv * 16 + rr;
        const int grow = row0 + lrow;
        if (grow >= N_NODES) break;
        float2 vv = *(const float2*)&Hs[lrow][l * 2];
        vv.x += b2.x; vv.y += b2.y;
        orib[(size_t)grow * 64 + l] = pack_bf16x2(vv.x, vv.y);
        float s  = vv.x + vv.y;
        float s2 = vv.x * vv.x + vv.y * vv.y;
#pragma unroll
        for (int m = 1; m < 64; m <<= 1) {
            s  += __shfl_xor(s, m);
            s2 += __shfl_xor(s2, m);
        }
        const float mu   = s * (1.0f / 128.0f);
        const float var  = s2 * (1.0f / 128.0f) - mu * mu;
        const float rstd = rsqrtf(var + LN_EPS);
        float y0 = fmaxf((vv.x - mu) * rstd * sc2.x + bb2.x, 0.0f);
        float y1 = fmaxf((vv.y - mu) * rstd * sc2.y + bb2.y, 0.0f);
        hact[(size_t)grow * 64 + l] = pack_bf16x2(y0, y1);
    }
}

// ---------------- SpMM: 1 node/wave, scalar row bounds, 8-wide unroll ----------
// Each gather instruction touches exactly one contiguous 256B bf16 row.
#define SPMM_ACC(cc)                                                      \
    {                                                                     \
        unsigned v = Hb[(size_t)(cc).x * 64 + lane];                      \
        float w = __int_as_float((cc).y);                                 \
        accx += w * bflo(v);                                              \
        accy += w * bfhi(v);                                              \
    }

__device__ inline void spmm_row(const int2* __restrict__ csr,
                                const unsigned* __restrict__ Hb,
                                int beg, int end, int lane,
                                float& accx, float& accy) {
    int e = beg;
    for (; e + 8 <= end; e += 8) {
        int2 c0 = csr[e],     c1 = csr[e + 1], c2 = csr[e + 2], c3 = csr[e + 3];
        int2 c4 = csr[e + 4], c5 = csr[e + 5], c6 = csr[e + 6], c7 = csr[e + 7];
        SPMM_ACC(c0) SPMM_ACC(c1) SPMM_ACC(c2) SPMM_ACC(c3)
        SPMM_ACC(c4) SPMM_ACC(c5) SPMM_ACC(c6) SPMM_ACC(c7)
    }
    for (; e + 2 <= end; e += 2) {
        int2 c0 = csr[e], c1 = csr[e + 1];
        SPMM_ACC(c0) SPMM_ACC(c1)
    }
    if (e < end) {
        int2 c0 = csr[e];
        SPMM_ACC(c0)
    }
}

__global__ __launch_bounds__(256) void k_spmm_ln(const int* __restrict__ rp,
                                                 const int2* __restrict__ csr,
                                                 const unsigned* __restrict__ Hb,
                                                 const unsigned* __restrict__ orib,
                                                 const float* __restrict__ lns,
                                                 const float* __restrict__ lnb,
                                                 unsigned* __restrict__ hout) {
    const int wid  = (blockIdx.x * 256 + threadIdx.x) >> 6;
    const int lane = threadIdx.x & 63;

    const int beg = __builtin_amdgcn_readfirstlane(rp[wid]);
    const int end = __builtin_amdgcn_readfirstlane(rp[wid + 1]);

    float accx = 0.f, accy = 0.f;
    spmm_row(csr, Hb, beg, end, lane, accx, accy);

    // residual (bf16) + LN + ReLU -> bf16
    unsigned o = orib[(size_t)wid * 64 + lane];
    float vx = accx + bflo(o), vy = accy + bfhi(o);
    float s  = vx + vy;
    float s2 = vx * vx + vy * vy;
#pragma unroll
    for (int m = 1; m < 64; m <<= 1) {
        s  += __shfl_xor(s, m);
        s2 += __shfl_xor(s2, m);
    }
    const float mu   = s * (1.0f / 128.0f);
    const float var  = s2 * (1.0f / 128.0f) - mu * mu;
    const float rstd = rsqrtf(var + LN_EPS);
    const float2 sc = ((const float2*)lns)[lane];
    const float2 bb = ((const float2*)lnb)[lane];
    float y0 = fmaxf((vx - mu) * rstd * sc.x + bb.x, 0.0f);
    float y1 = fmaxf((vy - mu) * rstd * sc.y + bb.y, 0.0f);
    hout[(size_t)wid * 64 + lane] = pack_bf16x2(y0, y1);
}

__global__ __launch_bounds__(256) void k_spmm_out(const int* __restrict__ rp,
                                                  const int2* __restrict__ csr,
                                                  const unsigned* __restrict__ Hb,
                                                  float* __restrict__ out) {
    const int wid  = (blockIdx.x * 256 + threadIdx.x) >> 6;
    const int lane = threadIdx.x & 63;

    const int beg = __builtin_amdgcn_readfirstlane(rp[wid]);
    const int end = __builtin_amdgcn_readfirstlane(rp[wid + 1]);

    float accx = 0.f, accy = 0.f;
    spmm_row(csr, Hb, beg, end, lane, accx, accy);

    ((float2*)out)[(size_t)wid * 64 + lane] = make_float2(accx, accy);
}

extern "C" void kernel_launch(void* const* d_in, const int* in_sizes, int n_in,
                              void* d_out, int out_size, void* d_ws, size_t ws_size,
                              hipStream_t stream) {
    const float* x   = (const float*)d_in[0];
    const int*   ei  = (const int*)d_in[1];
    const float* ef  = (const float*)d_in[2];
    const float* W   = (const float*)d_in[3];
    const float* b   = (const float*)d_in[4];
    const float* lns = (const float*)d_in[5];
    const float* lnb = (const float*)d_in[6];
    float* out = (float*)d_out;

    // bf16 residual parked in d_out's first 25.6MB (read by spmm_ln, then d_out
    // fully overwritten by spmm_out)
    unsigned* orib = (unsigned*)d_out;

    unsigned* hact  = (unsigned*)d_ws;                          // N*64 u32
    unsigned* hact2 = hact + (size_t)N_NODES * 64;              // N*64 u32
    int2* csr    = (int2*)(hact2 + (size_t)N_NODES * 64);       // E
    int2* gbufSW = csr + N_EDGES;                               // NBKT*BCAP
    int* gcur    = (int*)(gbufSW + (size_t)NBKT * BCAP);        // NBKT
    int* rp      = gcur + NBKT;                                 // N+1
    int* gbufDst = rp + (N_NODES + 1);                          // NBKT*BCAP

    const int wb = N_NODES * 64 / 256;                          // 25000 blocks

    hipMemsetAsync(gcur, 0, NBKT * sizeof(int), stream);
    k_bin<<<256, 256, 0, stream>>>(ei, ef, gcur, gbufDst, gbufSW);
    k_build<<<NBKT, 512, 0, stream>>>(gcur, gbufDst, gbufSW, rp, csr);

    k_gemm_mfma<<<(N_NODES + 63) / 64, 256, 0, stream>>>(x, W, b, lns, lnb, orib, hact);

    k_spmm_ln<<<wb, 256, 0, stream>>>(rp, csr, hact, orib, lns + HID, lnb + HID, hact2);
    k_spmm_out<<<wb, 256, 0, stream>>>(rp, csr, hact2, out);
}